// Round 1
// baseline (22452.753 us; speedup 1.0000x reference)
//
#include <hip/hip_runtime.h>

#define TT 2048
#define BB 8
#define DD 1024
#define HH 1024

// ---------------- counter zeroing ----------------
__global__ __launch_bounds__(256) void zero_cnt_kernel(int* cnt) {
    int i = blockIdx.x * 256 + threadIdx.x;
    if (i < TT) cnt[i] = 0;
}

// ---------------- fused projection GEMMs ----------------
// xw_out[r][h]   = sum_k x[r][k]*Wx[h][k] + bias[h]        (written to d_out)
// decay_out[r][h]= sigmoid(-(sum_k x[r][k]*Wd[h][k] + bdel[h]))
#define BM 128
#define BN 64
#define BK 16

__global__ __launch_bounds__(256) void proj_kernel(
    const float* __restrict__ x, const float* __restrict__ Wx,
    const float* __restrict__ Wd, const float* __restrict__ bias,
    const float* __restrict__ bdel, float* __restrict__ xw_out,
    float* __restrict__ decay_out)
{
    __shared__ float As[BM][BK + 1];
    __shared__ float Bxs[BN][BK + 1];
    __shared__ float Bds[BN][BK + 1];

    const int bm = blockIdx.y * BM;
    const int bn = blockIdx.x * BN;
    const int tid = threadIdx.x;
    const int tx = tid & 15, ty = tid >> 4;

    float accx[8][4] = {};
    float accd[8][4] = {};

    for (int k0 = 0; k0 < DD; k0 += BK) {
        // stage A tile: 128x16 floats = 512 float4, 2 per thread
#pragma unroll
        for (int l = 0; l < 2; ++l) {
            const int f = tid + l * 256;
            const int row = f >> 2, kc = (f & 3) * 4;
            const float4 v = *(const float4*)&x[(size_t)(bm + row) * DD + k0 + kc];
            As[row][kc + 0] = v.x; As[row][kc + 1] = v.y;
            As[row][kc + 2] = v.z; As[row][kc + 3] = v.w;
        }
        // stage B tiles: 64x16 each = 256 float4, 1 per thread per matrix
        {
            const int row = tid >> 2, kc = (tid & 3) * 4;
            float4 v = *(const float4*)&Wx[(size_t)(bn + row) * DD + k0 + kc];
            Bxs[row][kc + 0] = v.x; Bxs[row][kc + 1] = v.y;
            Bxs[row][kc + 2] = v.z; Bxs[row][kc + 3] = v.w;
            v = *(const float4*)&Wd[(size_t)(bn + row) * DD + k0 + kc];
            Bds[row][kc + 0] = v.x; Bds[row][kc + 1] = v.y;
            Bds[row][kc + 2] = v.z; Bds[row][kc + 3] = v.w;
        }
        __syncthreads();
#pragma unroll
        for (int k = 0; k < BK; ++k) {
            float af[8], bxf[4], bdf[4];
#pragma unroll
            for (int i = 0; i < 8; ++i) af[i] = As[ty * 8 + i][k];
#pragma unroll
            for (int j = 0; j < 4; ++j) { bxf[j] = Bxs[tx * 4 + j][k]; bdf[j] = Bds[tx * 4 + j][k]; }
#pragma unroll
            for (int i = 0; i < 8; ++i)
#pragma unroll
                for (int j = 0; j < 4; ++j) {
                    accx[i][j] += af[i] * bxf[j];
                    accd[i][j] += af[i] * bdf[j];
                }
        }
        __syncthreads();
    }

    // epilogue: add bias; decay = 1/(1+exp(delta_raw)) == exp(-softplus(dr))
#pragma unroll
    for (int i = 0; i < 8; ++i) {
        const int row = bm + ty * 8 + i;
        const int col0 = bn + tx * 4;
        float4 xo, dc;
        xo.x = accx[i][0] + bias[col0 + 0];
        xo.y = accx[i][1] + bias[col0 + 1];
        xo.z = accx[i][2] + bias[col0 + 2];
        xo.w = accx[i][3] + bias[col0 + 3];
        dc.x = 1.0f / (1.0f + expf(accd[i][0] + bdel[col0 + 0]));
        dc.y = 1.0f / (1.0f + expf(accd[i][1] + bdel[col0 + 1]));
        dc.z = 1.0f / (1.0f + expf(accd[i][2] + bdel[col0 + 2]));
        dc.w = 1.0f / (1.0f + expf(accd[i][3] + bdel[col0 + 3]));
        *(float4*)&xw_out[(size_t)row * HH + col0] = xo;
        *(float4*)&decay_out[(size_t)row * HH + col0] = dc;
    }
}

// ---------------- sequential scan ----------------
// 64 blocks x 256 threads. Block owns 16 channels for all 8 batches.
// Thread (c = tid&15, ks = tid>>4) holds R[ch][ks*64 .. ks*64+63] in regs.
// h staged into LDS each step (skewed: stride 76 floats per 64-slice).
#define NBLK 64
#define CPB 16
#define HSTR 1216   // 16 * 76 per batch row

__global__ __launch_bounds__(256) void scan_kernel(
    const float* __restrict__ h0, const float* __restrict__ R,
    const float* __restrict__ decay, float* out, int* cnt)
{
    __shared__ __align__(16) float hbuf[BB * HSTR];      // 38912 B
    __shared__ float red[BB][16][CPB + 1];               // 8704 B

    const int tid = threadIdx.x;
    const int c = tid & 15, ks = tid >> 4;
    const int ch = blockIdx.x * CPB + c;

    // one-time: R row slice into registers
    float rreg[64];
#pragma unroll
    for (int q = 0; q < 16; ++q) {
        const float4 v = *(const float4*)&R[(size_t)ch * HH + ks * 64 + q * 4];
        rreg[4 * q + 0] = v.x; rreg[4 * q + 1] = v.y;
        rreg[4 * q + 2] = v.z; rreg[4 * q + 3] = v.w;
    }

    for (int t = 0; t < TT; ++t) {
        if (t > 0) {
            if (tid == 0) {
                while (__hip_atomic_load(&cnt[t - 1], __ATOMIC_ACQUIRE,
                                         __HIP_MEMORY_SCOPE_AGENT) != NBLK) {
                    __builtin_amdgcn_s_sleep(2);
                }
            }
            __syncthreads();
            __threadfence();   // acquire side: invalidate stale cache lines
        }
        const float* hsrc = (t == 0) ? h0 : (out + (size_t)(t - 1) * BB * HH);

        // stage full h (8x1024) into LDS, skewed layout
#pragma unroll
        for (int b = 0; b < BB; ++b) {
            const float4 v = *(const float4*)&hsrc[b * HH + tid * 4];
            const int ph = b * HSTR + (tid >> 4) * 76 + ((tid * 4) & 63);
            *(float4*)&hbuf[ph] = v;
        }
        __syncthreads();

        // partial dots: this thread covers K-slice [ks*64, ks*64+64) for 8 batches
        float acc[BB] = {};
#pragma unroll
        for (int q = 0; q < 16; ++q) {
#pragma unroll
            for (int b = 0; b < BB; ++b) {
                const float4 h4 = *(const float4*)&hbuf[b * HSTR + ks * 76 + q * 4];
                acc[b] += rreg[4 * q + 0] * h4.x + rreg[4 * q + 1] * h4.y
                        + rreg[4 * q + 2] * h4.z + rreg[4 * q + 3] * h4.w;
            }
        }
#pragma unroll
        for (int b = 0; b < BB; ++b) red[b][ks][c] = acc[b];
        __syncthreads();

        // final reduce + pointwise, 128 threads (one per (b, channel))
        if (tid < 128) {
            const int cc = tid & 15, b = tid >> 4;
            float s = 0.f;
#pragma unroll
            for (int k2 = 0; k2 < 16; ++k2) s += red[b][k2][cc];
            const int gch = blockIdx.x * CPB + cc;
            const size_t oidx = (size_t)t * BB * HH + (size_t)b * HH + gch;
            const float xw = out[oidx];          // projection, still intact
            const float d = decay[oidx];
            const float hp = hbuf[b * HSTR + (gch >> 6) * 76 + (gch & 63)];
            const float cand = tanhf(s + xw);
            out[oidx] = d * hp + (1.0f - d) * cand;
        }
        __syncthreads();
        if (tid == 0) {
            __threadfence();  // release: make this block's h slice visible
            __hip_atomic_fetch_add(&cnt[t], 1, __ATOMIC_RELEASE,
                                   __HIP_MEMORY_SCOPE_AGENT);
        }
    }
}

// ---------------- launch ----------------
extern "C" void kernel_launch(void* const* d_in, const int* in_sizes, int n_in,
                              void* d_out, int out_size, void* d_ws, size_t ws_size,
                              hipStream_t stream) {
    const float* x    = (const float*)d_in[0];
    const float* h0   = (const float*)d_in[1];
    const float* Wx   = (const float*)d_in[2];
    const float* R    = (const float*)d_in[3];
    const float* bias = (const float*)d_in[4];
    const float* Wd   = (const float*)d_in[5];
    const float* bdel = (const float*)d_in[6];
    float* out = (float*)d_out;

    float* decay = (float*)d_ws;                                  // 67108864 B
    int* cnt = (int*)((char*)d_ws + (size_t)TT * BB * HH * 4);    // 8192 B

    zero_cnt_kernel<<<(TT + 255) / 256, 256, 0, stream>>>(cnt);
    proj_kernel<<<dim3(HH / BN, (TT * BB) / BM), 256, 0, stream>>>(
        x, Wx, Wd, bias, bdel, out, decay);
    scan_kernel<<<NBLK, 256, 0, stream>>>(h0, R, decay, out, cnt);
}

// Round 2
// 20721.103 us; speedup vs baseline: 1.0836x; 1.0836x over previous
//
#include <hip/hip_runtime.h>

#define TT 2048
#define BB 8
#define DD 1024
#define HH 1024

typedef unsigned long long u64;

// ---------------- flag zeroing ----------------
__global__ __launch_bounds__(64) void zero_cnt_kernel(int* flag) {
    flag[threadIdx.x] = 0;
}

// ---------------- fused projection GEMMs ----------------
// xw_out[r][h]   = sum_k x[r][k]*Wx[h][k] + bias[h]        (written to d_out)
// decay_out[r][h]= sigmoid(-(sum_k x[r][k]*Wd[h][k] + bdel[h]))
#define BM 128
#define BN 64
#define BK 16

__global__ __launch_bounds__(256) void proj_kernel(
    const float* __restrict__ x, const float* __restrict__ Wx,
    const float* __restrict__ Wd, const float* __restrict__ bias,
    const float* __restrict__ bdel, float* __restrict__ xw_out,
    float* __restrict__ decay_out)
{
    __shared__ float As[BM][BK + 1];
    __shared__ float Bxs[BN][BK + 1];
    __shared__ float Bds[BN][BK + 1];

    const int bm = blockIdx.y * BM;
    const int bn = blockIdx.x * BN;
    const int tid = threadIdx.x;
    const int tx = tid & 15, ty = tid >> 4;

    float accx[8][4] = {};
    float accd[8][4] = {};

    for (int k0 = 0; k0 < DD; k0 += BK) {
#pragma unroll
        for (int l = 0; l < 2; ++l) {
            const int f = tid + l * 256;
            const int row = f >> 2, kc = (f & 3) * 4;
            const float4 v = *(const float4*)&x[(size_t)(bm + row) * DD + k0 + kc];
            As[row][kc + 0] = v.x; As[row][kc + 1] = v.y;
            As[row][kc + 2] = v.z; As[row][kc + 3] = v.w;
        }
        {
            const int row = tid >> 2, kc = (tid & 3) * 4;
            float4 v = *(const float4*)&Wx[(size_t)(bn + row) * DD + k0 + kc];
            Bxs[row][kc + 0] = v.x; Bxs[row][kc + 1] = v.y;
            Bxs[row][kc + 2] = v.z; Bxs[row][kc + 3] = v.w;
            v = *(const float4*)&Wd[(size_t)(bn + row) * DD + k0 + kc];
            Bds[row][kc + 0] = v.x; Bds[row][kc + 1] = v.y;
            Bds[row][kc + 2] = v.z; Bds[row][kc + 3] = v.w;
        }
        __syncthreads();
#pragma unroll
        for (int k = 0; k < BK; ++k) {
            float af[8], bxf[4], bdf[4];
#pragma unroll
            for (int i = 0; i < 8; ++i) af[i] = As[ty * 8 + i][k];
#pragma unroll
            for (int j = 0; j < 4; ++j) { bxf[j] = Bxs[tx * 4 + j][k]; bdf[j] = Bds[tx * 4 + j][k]; }
#pragma unroll
            for (int i = 0; i < 8; ++i)
#pragma unroll
                for (int j = 0; j < 4; ++j) {
                    accx[i][j] += af[i] * bxf[j];
                    accd[i][j] += af[i] * bdf[j];
                }
        }
        __syncthreads();
    }

#pragma unroll
    for (int i = 0; i < 8; ++i) {
        const int row = bm + ty * 8 + i;
        const int col0 = bn + tx * 4;
        float4 xo, dc;
        xo.x = accx[i][0] + bias[col0 + 0];
        xo.y = accx[i][1] + bias[col0 + 1];
        xo.z = accx[i][2] + bias[col0 + 2];
        xo.w = accx[i][3] + bias[col0 + 3];
        dc.x = 1.0f / (1.0f + expf(accd[i][0] + bdel[col0 + 0]));
        dc.y = 1.0f / (1.0f + expf(accd[i][1] + bdel[col0 + 1]));
        dc.z = 1.0f / (1.0f + expf(accd[i][2] + bdel[col0 + 2]));
        dc.w = 1.0f / (1.0f + expf(accd[i][3] + bdel[col0 + 3]));
        *(float4*)&xw_out[(size_t)row * HH + col0] = xo;
        *(float4*)&decay_out[(size_t)row * HH + col0] = dc;
    }
}

// ---------------- sequential scan ----------------
// 64 blocks x 256 threads; block owns 16 channels x 8 batches.
// Cross-block h exchange via device-coherent (sc1) relaxed atomics only —
// NO fences, NO L2 writeback/invalidate. Per-block flag array, 64-lane poll.
#define NBLK 64
#define CPB 16
#define HSTR 1216   // 16 * 76 floats per batch row (skewed to dodge bank conflicts)

__device__ __forceinline__ float4 f4_from_2u64(u64 lo, u64 hi) {
    float4 v;
    v.x = __uint_as_float((unsigned)(lo & 0xffffffffu));
    v.y = __uint_as_float((unsigned)(lo >> 32));
    v.z = __uint_as_float((unsigned)(hi & 0xffffffffu));
    v.w = __uint_as_float((unsigned)(hi >> 32));
    return v;
}

__global__ __launch_bounds__(256) void scan_kernel(
    const float* __restrict__ h0, const float* __restrict__ R,
    const float* __restrict__ decay, float* out, int* flag)
{
    __shared__ __align__(16) float hbuf[BB * HSTR];      // 38912 B
    __shared__ float red[BB][16][CPB + 1];               // 8704 B

    const int tid = threadIdx.x;
    const int c = tid & 15, ks = tid >> 4;
    const int ch = blockIdx.x * CPB + c;

    // one-time: R row slice into registers (64 floats)
    float rreg[64];
#pragma unroll
    for (int q = 0; q < 16; ++q) {
        const float4 v = *(const float4*)&R[(size_t)ch * HH + ks * 64 + q * 4];
        rreg[4 * q + 0] = v.x; rreg[4 * q + 1] = v.y;
        rreg[4 * q + 2] = v.z; rreg[4 * q + 3] = v.w;
    }

    // epilogue thread mapping (tid < 128): one (batch, channel) pair
    const int ecc = tid & 15, eb = tid >> 4;       // eb in 0..7 for tid<128
    const int egch = blockIdx.x * CPB + ecc;

    for (int t = 0; t < TT; ++t) {
        // ---- wait for step t-1 from all blocks (64 parallel flag polls) ----
        if (t > 0 && tid < NBLK) {
            while (__hip_atomic_load(&flag[tid], __ATOMIC_RELAXED,
                                     __HIP_MEMORY_SCOPE_AGENT) < t) {
                __builtin_amdgcn_s_sleep(1);
            }
        }
        __syncthreads();

        // ---- prefetch own xw/decay (race-free, cached) ----
        float xw_pref = 0.f, d_pref = 0.f;
        size_t oidx = 0;
        if (tid < 128) {
            oidx = (size_t)t * BB * HH + (size_t)eb * HH + egch;
            xw_pref = out[oidx];       // projection value, still intact
            d_pref = decay[oidx];
        }

        // ---- stage h_{t-1} (8x1024 f32) into LDS via device-coherent loads ----
        const u64* hsrc = (t == 0) ? (const u64*)h0
                                   : (const u64*)(out + (size_t)(t - 1) * BB * HH);
#pragma unroll
        for (int b = 0; b < BB; ++b) {
            const u64 lo = __hip_atomic_load(&hsrc[b * 512 + tid * 2],
                                             __ATOMIC_RELAXED, __HIP_MEMORY_SCOPE_AGENT);
            const u64 hi = __hip_atomic_load(&hsrc[b * 512 + tid * 2 + 1],
                                             __ATOMIC_RELAXED, __HIP_MEMORY_SCOPE_AGENT);
            const int ph = b * HSTR + (tid >> 4) * 76 + ((tid * 4) & 63);
            *(float4*)&hbuf[ph] = f4_from_2u64(lo, hi);
        }
        __syncthreads();

        // ---- partial dots: K-slice [ks*64, ks*64+64) for 8 batches ----
        float acc[BB] = {};
#pragma unroll
        for (int q = 0; q < 16; ++q) {
#pragma unroll
            for (int b = 0; b < BB; ++b) {
                const float4 h4 = *(const float4*)&hbuf[b * HSTR + ks * 76 + q * 4];
                acc[b] += rreg[4 * q + 0] * h4.x + rreg[4 * q + 1] * h4.y
                        + rreg[4 * q + 2] * h4.z + rreg[4 * q + 3] * h4.w;
            }
        }
#pragma unroll
        for (int b = 0; b < BB; ++b) red[b][ks][c] = acc[b];
        __syncthreads();

        // ---- final reduce + pointwise + device-coherent store ----
        if (tid < 128) {
            float s = 0.f;
#pragma unroll
            for (int k2 = 0; k2 < 16; ++k2) s += red[eb][k2][ecc];
            const float hp = hbuf[eb * HSTR + (egch >> 6) * 76 + (egch & 63)];
            const float cand = tanhf(s + xw_pref);
            const float hnew = d_pref * hp + (1.0f - d_pref) * cand;
            __hip_atomic_store(&out[oidx], hnew, __ATOMIC_RELAXED,
                               __HIP_MEMORY_SCOPE_AGENT);
        }
        // drain this wave's sc1 stores so the flag can't pass them
        asm volatile("s_waitcnt vmcnt(0)" ::: "memory");
        __syncthreads();
        if (tid == 0) {
            __hip_atomic_store(&flag[blockIdx.x], t + 1, __ATOMIC_RELAXED,
                               __HIP_MEMORY_SCOPE_AGENT);
        }
    }
}

// ---------------- launch ----------------
extern "C" void kernel_launch(void* const* d_in, const int* in_sizes, int n_in,
                              void* d_out, int out_size, void* d_ws, size_t ws_size,
                              hipStream_t stream) {
    const float* x    = (const float*)d_in[0];
    const float* h0   = (const float*)d_in[1];
    const float* Wx   = (const float*)d_in[2];
    const float* R    = (const float*)d_in[3];
    const float* bias = (const float*)d_in[4];
    const float* Wd   = (const float*)d_in[5];
    const float* bdel = (const float*)d_in[6];
    float* out = (float*)d_out;

    float* decay = (float*)d_ws;                                  // 67108864 B
    int* flag = (int*)((char*)d_ws + (size_t)TT * BB * HH * 4);   // 256 B

    zero_cnt_kernel<<<1, 64, 0, stream>>>(flag);
    proj_kernel<<<dim3(HH / BN, (TT * BB) / BM), 256, 0, stream>>>(
        x, Wx, Wd, bias, bdel, out, decay);
    scan_kernel<<<NBLK, 256, 0, stream>>>(h0, R, decay, out, flag);
}

// Round 3
// 11459.262 us; speedup vs baseline: 1.9594x; 1.8082x over previous
//
#include <hip/hip_runtime.h>

#define TT 2048
#define BB 8
#define DD 1024
#define HH 1024

typedef unsigned long long u64;
typedef float f32x4 __attribute__((ext_vector_type(4)));

// ---------------- flag zeroing ----------------
__global__ __launch_bounds__(128) void zero_cnt_kernel(int* flag) {
    flag[threadIdx.x] = 0;
}

// ---------------- fused projection GEMMs ----------------
#define BM 128
#define BN 64
#define BK 16

__global__ __launch_bounds__(256) void proj_kernel(
    const float* __restrict__ x, const float* __restrict__ Wx,
    const float* __restrict__ Wd, const float* __restrict__ bias,
    const float* __restrict__ bdel, float* __restrict__ xw_out,
    float* __restrict__ decay_out)
{
    __shared__ float As[BM][BK + 1];
    __shared__ float Bxs[BN][BK + 1];
    __shared__ float Bds[BN][BK + 1];

    const int bm = blockIdx.y * BM;
    const int bn = blockIdx.x * BN;
    const int tid = threadIdx.x;
    const int tx = tid & 15, ty = tid >> 4;

    float accx[8][4] = {};
    float accd[8][4] = {};

    for (int k0 = 0; k0 < DD; k0 += BK) {
#pragma unroll
        for (int l = 0; l < 2; ++l) {
            const int f = tid + l * 256;
            const int row = f >> 2, kc = (f & 3) * 4;
            const float4 v = *(const float4*)&x[(size_t)(bm + row) * DD + k0 + kc];
            As[row][kc + 0] = v.x; As[row][kc + 1] = v.y;
            As[row][kc + 2] = v.z; As[row][kc + 3] = v.w;
        }
        {
            const int row = tid >> 2, kc = (tid & 3) * 4;
            float4 v = *(const float4*)&Wx[(size_t)(bn + row) * DD + k0 + kc];
            Bxs[row][kc + 0] = v.x; Bxs[row][kc + 1] = v.y;
            Bxs[row][kc + 2] = v.z; Bxs[row][kc + 3] = v.w;
            v = *(const float4*)&Wd[(size_t)(bn + row) * DD + k0 + kc];
            Bds[row][kc + 0] = v.x; Bds[row][kc + 1] = v.y;
            Bds[row][kc + 2] = v.z; Bds[row][kc + 3] = v.w;
        }
        __syncthreads();
#pragma unroll
        for (int k = 0; k < BK; ++k) {
            float af[8], bxf[4], bdf[4];
#pragma unroll
            for (int i = 0; i < 8; ++i) af[i] = As[ty * 8 + i][k];
#pragma unroll
            for (int j = 0; j < 4; ++j) { bxf[j] = Bxs[tx * 4 + j][k]; bdf[j] = Bds[tx * 4 + j][k]; }
#pragma unroll
            for (int i = 0; i < 8; ++i)
#pragma unroll
                for (int j = 0; j < 4; ++j) {
                    accx[i][j] += af[i] * bxf[j];
                    accd[i][j] += af[i] * bdf[j];
                }
        }
        __syncthreads();
    }

#pragma unroll
    for (int i = 0; i < 8; ++i) {
        const int row = bm + ty * 8 + i;
        const int col0 = bn + tx * 4;
        float4 xo, dc;
        xo.x = accx[i][0] + bias[col0 + 0];
        xo.y = accx[i][1] + bias[col0 + 1];
        xo.z = accx[i][2] + bias[col0 + 2];
        xo.w = accx[i][3] + bias[col0 + 3];
        dc.x = 1.0f / (1.0f + expf(accd[i][0] + bdel[col0 + 0]));
        dc.y = 1.0f / (1.0f + expf(accd[i][1] + bdel[col0 + 1]));
        dc.z = 1.0f / (1.0f + expf(accd[i][2] + bdel[col0 + 2]));
        dc.w = 1.0f / (1.0f + expf(accd[i][3] + bdel[col0 + 3]));
        *(float4*)&xw_out[(size_t)row * HH + col0] = xo;
        *(float4*)&decay_out[(size_t)row * HH + col0] = dc;
    }
}

// ---------------- sequential scan ----------------
// 64 blocks x 256 threads; block owns 16 channels x 8 batches.
// Thread (cp=tid&7, ks=tid>>3): channels {blk*16+2cp, +1}, K-slice [ks*32,+32).
// All cross-block traffic via sc0/sc1 (coherence-point) loads/stores; no fences.
#define NBLK 64
#define CPB 16
#define HSTR 1216   // 16*76 floats per batch row (skew kills bank conflicts)

__global__ __launch_bounds__(256, 1) void scan_kernel(
    const float* __restrict__ h0, const float* __restrict__ R,
    const float* __restrict__ decay, float* out, int* flag2)
{
    __shared__ __align__(16) float hbuf[BB * HSTR];   // 38912 B
    __shared__ __align__(16) float red2[512];         // 2048 B

    const int tid = threadIdx.x;
    const int cp = tid & 7;        // channel pair id
    const int ks = tid >> 3;       // 0..31, K-slice of 32 floats
    const int ch0 = blockIdx.x * CPB + cp * 2;

    // one-time: R rows for 2 channels, this thread's K-slice (64 floats)
    float rreg[2][32];
#pragma unroll
    for (int i = 0; i < 2; ++i)
#pragma unroll
        for (int q = 0; q < 8; ++q) {
            const f32x4 v = *(const f32x4*)&R[(size_t)(ch0 + i) * HH + ks * 32 + q * 4];
            rreg[i][q * 4 + 0] = v.x; rreg[i][q * 4 + 1] = v.y;
            rreg[i][q * 4 + 2] = v.z; rreg[i][q * 4 + 3] = v.w;
        }

    // staging LDS offset (floats), skewed
    const int phbase = (tid >> 4) * 76 + ((tid * 4) & 63);
    // dot-phase base offset
    const int dbase = (ks >> 1) * 76 + (ks & 1) * 32;

    // epilogue mapping (tid < 128): one (batch, channel)
    const int ech = tid & 15, eb = tid >> 4;
    const int egch = blockIdx.x * CPB + ech;
    const int ridx = (ech >> 1) * 16 + (ech & 1) * 8 + eb;
    const int hpoff = eb * HSTR + (egch >> 6) * 76 + (egch & 63);

    for (int t = 0; t < TT; ++t) {
        // ---- prefetch own xw/decay (race-free) BEFORE the poll ----
        float xw_pref = 0.f, d_pref = 0.f;
        size_t oidx = 0;
        if (tid < 128) {
            oidx = (size_t)t * (BB * HH) + (size_t)eb * HH + egch;
            xw_pref = out[oidx];      // projection value, still intact
            d_pref = decay[oidx];
        }
        // ---- wait for step t-1: 128 per-wave flags, 128 polling lanes ----
        if (t > 0 && tid < 128) {
            while (__hip_atomic_load(&flag2[tid], __ATOMIC_RELAXED,
                                     __HIP_MEMORY_SCOPE_AGENT) < t) {}
        }
        __syncthreads();

        // ---- stage h_{t-1} (8x1024 f32): 8 pipelined coherent 16B loads ----
        const u64 hbase = (u64)(t == 0 ? (const void*)h0
                                       : (const void*)(out + (size_t)(t - 1) * (BB * HH)))
                          + (u64)tid * 16;
        f32x4 v0, v1, v2, v3, v4, v5, v6, v7;
        asm volatile("global_load_dwordx4 %0, %1, off sc0 sc1" : "=v"(v0) : "v"(hbase));
        asm volatile("global_load_dwordx4 %0, %1, off sc0 sc1" : "=v"(v1) : "v"(hbase + 4096));
        asm volatile("global_load_dwordx4 %0, %1, off sc0 sc1" : "=v"(v2) : "v"(hbase + 8192));
        asm volatile("global_load_dwordx4 %0, %1, off sc0 sc1" : "=v"(v3) : "v"(hbase + 12288));
        asm volatile("global_load_dwordx4 %0, %1, off sc0 sc1" : "=v"(v4) : "v"(hbase + 16384));
        asm volatile("global_load_dwordx4 %0, %1, off sc0 sc1" : "=v"(v5) : "v"(hbase + 20480));
        asm volatile("global_load_dwordx4 %0, %1, off sc0 sc1" : "=v"(v6) : "v"(hbase + 24576));
        asm volatile("global_load_dwordx4 %0, %1, off sc0 sc1" : "=v"(v7) : "v"(hbase + 28672));
        asm volatile("s_waitcnt vmcnt(0)" ::: "memory");
        __builtin_amdgcn_sched_barrier(0);
        *(f32x4*)&hbuf[phbase + 0 * HSTR] = v0;
        *(f32x4*)&hbuf[phbase + 1 * HSTR] = v1;
        *(f32x4*)&hbuf[phbase + 2 * HSTR] = v2;
        *(f32x4*)&hbuf[phbase + 3 * HSTR] = v3;
        *(f32x4*)&hbuf[phbase + 4 * HSTR] = v4;
        *(f32x4*)&hbuf[phbase + 5 * HSTR] = v5;
        *(f32x4*)&hbuf[phbase + 6 * HSTR] = v6;
        *(f32x4*)&hbuf[phbase + 7 * HSTR] = v7;
        __syncthreads();

        // ---- partial dots: 2 channels x 32 K x 8 batches per thread ----
        float acc0[8] = {}, acc1[8] = {};
#pragma unroll
        for (int b = 0; b < 8; ++b) {
#pragma unroll
            for (int q = 0; q < 8; ++q) {
                const f32x4 h4 = *(const f32x4*)&hbuf[b * HSTR + dbase + q * 4];
                acc0[b] += rreg[0][q * 4 + 0] * h4.x + rreg[0][q * 4 + 1] * h4.y
                         + rreg[0][q * 4 + 2] * h4.z + rreg[0][q * 4 + 3] * h4.w;
                acc1[b] += rreg[1][q * 4 + 0] * h4.x + rreg[1][q * 4 + 1] * h4.y
                         + rreg[1][q * 4 + 2] * h4.z + rreg[1][q * 4 + 3] * h4.w;
            }
        }
        // intra-wave butterfly over the 8 K-slices sharing this cp
#pragma unroll
        for (int b = 0; b < 8; ++b) {
            acc0[b] += __shfl_xor(acc0[b], 8, 64);
            acc0[b] += __shfl_xor(acc0[b], 16, 64);
            acc0[b] += __shfl_xor(acc0[b], 32, 64);
            acc1[b] += __shfl_xor(acc1[b], 8, 64);
            acc1[b] += __shfl_xor(acc1[b], 16, 64);
            acc1[b] += __shfl_xor(acc1[b], 32, 64);
        }
        if ((tid & 63) < 8) {   // one lane per cp per wave
            float* dst = &red2[(tid >> 6) * 128 + cp * 16];
            *(f32x4*)&dst[0]  = (f32x4){acc0[0], acc0[1], acc0[2], acc0[3]};
            *(f32x4*)&dst[4]  = (f32x4){acc0[4], acc0[5], acc0[6], acc0[7]};
            *(f32x4*)&dst[8]  = (f32x4){acc1[0], acc1[1], acc1[2], acc1[3]};
            *(f32x4*)&dst[12] = (f32x4){acc1[4], acc1[5], acc1[6], acc1[7]};
        }
        __syncthreads();

        // ---- final combine + pointwise + coherent store ----
        if (tid < 128) {
            const float s = red2[ridx] + red2[128 + ridx]
                          + red2[256 + ridx] + red2[384 + ridx];
            const float hp = hbuf[hpoff];
            const float cand = tanhf(s + xw_pref);
            const float hnew = d_pref * hp + (1.0f - d_pref) * cand;
            __hip_atomic_store(&out[oidx], hnew, __ATOMIC_RELAXED,
                               __HIP_MEMORY_SCOPE_AGENT);
        }
        // per-wave drain, then per-wave flag (waves 0 and 1 hold all h stores)
        asm volatile("s_waitcnt vmcnt(0)" ::: "memory");
        if (tid == 0 || tid == 64) {
            __hip_atomic_store(&flag2[(tid >> 6) * 64 + (int)blockIdx.x], t + 1,
                               __ATOMIC_RELAXED, __HIP_MEMORY_SCOPE_AGENT);
        }
    }
}

// ---------------- launch ----------------
extern "C" void kernel_launch(void* const* d_in, const int* in_sizes, int n_in,
                              void* d_out, int out_size, void* d_ws, size_t ws_size,
                              hipStream_t stream) {
    const float* x    = (const float*)d_in[0];
    const float* h0   = (const float*)d_in[1];
    const float* Wx   = (const float*)d_in[2];
    const float* R    = (const float*)d_in[3];
    const float* bias = (const float*)d_in[4];
    const float* Wd   = (const float*)d_in[5];
    const float* bdel = (const float*)d_in[6];
    float* out = (float*)d_out;

    float* decay = (float*)d_ws;                                   // 67108864 B
    int* flag2 = (int*)((char*)d_ws + (size_t)TT * BB * HH * 4);   // 512 B

    zero_cnt_kernel<<<1, 128, 0, stream>>>(flag2);
    proj_kernel<<<dim3(HH / BN, (TT * BB) / BM), 256, 0, stream>>>(
        x, Wx, Wd, bias, bdel, out, decay);
    scan_kernel<<<NBLK, 256, 0, stream>>>(h0, R, decay, out, flag2);
}

// Round 4
// 9997.414 us; speedup vs baseline: 2.2459x; 1.1462x over previous
//
#include <hip/hip_runtime.h>

#define TT 2048
#define BB 8
#define DD 1024
#define HH 1024

typedef unsigned int u32;
typedef unsigned short u16;
typedef unsigned long long u64;
typedef float f32x4 __attribute__((ext_vector_type(4)));
typedef u32 u32x4 __attribute__((ext_vector_type(4)));
typedef _Float16 f16x8 __attribute__((ext_vector_type(8)));

union V4H8 { u32x4 u; f16x8 h; };

// ---------------- tag invalidation (every launch: no cross-call state) ----------------
__global__ __launch_bounds__(256) void clear_hb_kernel(u32* hb) {
    const int i = blockIdx.x * 256 + threadIdx.x;   // 64 blocks x 256 = 16384
    __hip_atomic_store(&hb[i], 0xFFFF0000u, __ATOMIC_RELAXED, __HIP_MEMORY_SCOPE_AGENT);
}

// ---------------- fused projection GEMMs (unchanged) ----------------
#define BM 128
#define BN 64
#define BK 16

__global__ __launch_bounds__(256) void proj_kernel(
    const float* __restrict__ x, const float* __restrict__ Wx,
    const float* __restrict__ Wd, const float* __restrict__ bias,
    const float* __restrict__ bdel, float* __restrict__ xw_out,
    float* __restrict__ decay_out)
{
    __shared__ float As[BM][BK + 1];
    __shared__ float Bxs[BN][BK + 1];
    __shared__ float Bds[BN][BK + 1];

    const int bm = blockIdx.y * BM;
    const int bn = blockIdx.x * BN;
    const int tid = threadIdx.x;
    const int tx = tid & 15, ty = tid >> 4;

    float accx[8][4] = {};
    float accd[8][4] = {};

    for (int k0 = 0; k0 < DD; k0 += BK) {
#pragma unroll
        for (int l = 0; l < 2; ++l) {
            const int f = tid + l * 256;
            const int row = f >> 2, kc = (f & 3) * 4;
            const float4 v = *(const float4*)&x[(size_t)(bm + row) * DD + k0 + kc];
            As[row][kc + 0] = v.x; As[row][kc + 1] = v.y;
            As[row][kc + 2] = v.z; As[row][kc + 3] = v.w;
        }
        {
            const int row = tid >> 2, kc = (tid & 3) * 4;
            float4 v = *(const float4*)&Wx[(size_t)(bn + row) * DD + k0 + kc];
            Bxs[row][kc + 0] = v.x; Bxs[row][kc + 1] = v.y;
            Bxs[row][kc + 2] = v.z; Bxs[row][kc + 3] = v.w;
            v = *(const float4*)&Wd[(size_t)(bn + row) * DD + k0 + kc];
            Bds[row][kc + 0] = v.x; Bds[row][kc + 1] = v.y;
            Bds[row][kc + 2] = v.z; Bds[row][kc + 3] = v.w;
        }
        __syncthreads();
#pragma unroll
        for (int k = 0; k < BK; ++k) {
            float af[8], bxf[4], bdf[4];
#pragma unroll
            for (int i = 0; i < 8; ++i) af[i] = As[ty * 8 + i][k];
#pragma unroll
            for (int j = 0; j < 4; ++j) { bxf[j] = Bxs[tx * 4 + j][k]; bdf[j] = Bds[tx * 4 + j][k]; }
#pragma unroll
            for (int i = 0; i < 8; ++i)
#pragma unroll
                for (int j = 0; j < 4; ++j) {
                    accx[i][j] += af[i] * bxf[j];
                    accd[i][j] += af[i] * bdf[j];
                }
        }
        __syncthreads();
    }

#pragma unroll
    for (int i = 0; i < 8; ++i) {
        const int row = bm + ty * 8 + i;
        const int col0 = bn + tx * 4;
        float4 xo, dc;
        xo.x = accx[i][0] + bias[col0 + 0];
        xo.y = accx[i][1] + bias[col0 + 1];
        xo.z = accx[i][2] + bias[col0 + 2];
        xo.w = accx[i][3] + bias[col0 + 3];
        dc.x = 1.0f / (1.0f + expf(accd[i][0] + bdel[col0 + 0]));
        dc.y = 1.0f / (1.0f + expf(accd[i][1] + bdel[col0 + 1]));
        dc.z = 1.0f / (1.0f + expf(accd[i][2] + bdel[col0 + 2]));
        dc.w = 1.0f / (1.0f + expf(accd[i][3] + bdel[col0 + 3]));
        *(float4*)&xw_out[(size_t)row * HH + col0] = xo;
        *(float4*)&decay_out[(size_t)row * HH + col0] = dc;
    }
}

// ---------------- sequential scan: MFMA + tag-in-data coherent broadcast ----------------
// 64 blocks x 256 threads (4 waves). Block owns 16 channels x 8 batches.
// Wave w covers K in [w*256, w*256+256) as 8 x mfma_f32_16x16x32_f16.
// A (R rows) lives in registers as fp16 fragments (loaded once).
// B (h_{t-1}) arrives as tagged u32 granules {tag16 | fp16} via sc0/sc1 loads,
// polled per-granule — the data IS the ready flag. Ping-pong 2 buffers.
#define NBLK 64
#define CPB 16

__global__ __launch_bounds__(256, 1) void scan_kernel(
    const float* __restrict__ h0, const float* __restrict__ R,
    const float* __restrict__ decay, float* __restrict__ out,
    u32* __restrict__ hb)
{
    __shared__ float cred[2][4][16][17];   // [pp][wave][ch row][batch col]

    const int tid = threadIdx.x;
    const int l = tid & 63;
    const int w = tid >> 6;          // wave 0..3 -> K range [w*256, +256)
    const int ar = l & 15;           // A row (channel in block) == C col index
    const int kg = l >> 4;           // 0..3: k sub-offset kg*8
    const int bb = l & 7;            // B batch (cols 8..15 duplicate 0..7)
    const int ch = blockIdx.x * CPB + ar;

    // ---- one-time: A fragments (R rows -> fp16), 8 frags = 32 VGPRs ----
    f16x8 afrag[8];
#pragma unroll
    for (int m = 0; m < 8; ++m) {
        const float* rp = &R[(size_t)ch * HH + w * 256 + m * 32 + kg * 8];
        const f32x4 r0 = *(const f32x4*)rp;
        const f32x4 r1 = *(const f32x4*)(rp + 4);
        f16x8 a;
        a[0] = (_Float16)r0.x; a[1] = (_Float16)r0.y;
        a[2] = (_Float16)r0.z; a[3] = (_Float16)r0.w;
        a[4] = (_Float16)r1.x; a[5] = (_Float16)r1.y;
        a[6] = (_Float16)r1.z; a[7] = (_Float16)r1.w;
        afrag[m] = a;
    }

    // per-lane byte offset into an h broadcast buffer (constant over t)
    const u64 laneoff = (u64)(bb * HH + w * 256 + kg * 8) * 4;

    // epilogue mapping (tid < 128): one (batch, channel)
    const int ech = tid & 15, eb = tid >> 4;
    const int egch = blockIdx.x * CPB + ech;

    float hp = 0.f;
    if (tid < 128) hp = h0[(size_t)eb * HH + egch];

    for (int t = 0; t < TT; ++t) {
        // ---- prefetch own xw/decay (race-free, cached) ----
        float xw_pref = 0.f, d_pref = 0.f;
        size_t oidx = 0;
        if (tid < 128) {
            oidx = (size_t)t * (BB * HH) + (size_t)eb * HH + egch;
            xw_pref = out[oidx];
            d_pref = decay[oidx];
        }

        // ---- acquire B fragments ----
        f16x8 bfrag[8];
        if (t == 0) {
#pragma unroll
            for (int m = 0; m < 8; ++m) {
                const float* hp0 = &h0[(size_t)bb * HH + w * 256 + m * 32 + kg * 8];
                const f32x4 h0a = *(const f32x4*)hp0;
                const f32x4 h0b = *(const f32x4*)(hp0 + 4);
                f16x8 b;
                b[0] = (_Float16)h0a.x; b[1] = (_Float16)h0a.y;
                b[2] = (_Float16)h0a.z; b[3] = (_Float16)h0a.w;
                b[4] = (_Float16)h0b.x; b[5] = (_Float16)h0b.y;
                b[6] = (_Float16)h0b.z; b[7] = (_Float16)h0b.w;
                bfrag[m] = b;
            }
        } else {
            const u32 tagv = (u32)(t - 1);
            const u64 gbase = (u64)hb + (u64)((t - 1) & 1) * (BB * HH * 4) + laneoff;
            u32x4 g0[8], g1[8];
            bool ok = false;
            do {
                if (!ok) {
#pragma unroll
                    for (int m = 0; m < 8; ++m) {
                        asm volatile("global_load_dwordx4 %0, %1, off sc0 sc1"
                                     : "=v"(g0[m]) : "v"(gbase + m * 128));
                        asm volatile("global_load_dwordx4 %0, %1, off sc0 sc1"
                                     : "=v"(g1[m]) : "v"(gbase + m * 128 + 16));
                    }
                    asm volatile("s_waitcnt vmcnt(0)" ::: "memory");
                    __builtin_amdgcn_sched_barrier(0);
                    ok = true;
#pragma unroll
                    for (int m = 0; m < 8; ++m)
#pragma unroll
                        for (int j = 0; j < 4; ++j) {
                            ok = ok && ((g0[m][j] >> 16) == tagv);
                            ok = ok && ((g1[m][j] >> 16) == tagv);
                        }
                }
            } while (!__all(ok));
#pragma unroll
            for (int m = 0; m < 8; ++m) {
                V4H8 cv;
                cv.u[0] = (g0[m][0] & 0xffffu) | (g0[m][1] << 16);
                cv.u[1] = (g0[m][2] & 0xffffu) | (g0[m][3] << 16);
                cv.u[2] = (g1[m][0] & 0xffffu) | (g1[m][1] << 16);
                cv.u[3] = (g1[m][2] & 0xffffu) | (g1[m][3] << 16);
                bfrag[m] = cv.h;
            }
        }

        // ---- 8 MFMAs: partial C[16ch x 16col] over this wave's K range ----
        f32x4 acc = {0.f, 0.f, 0.f, 0.f};
#pragma unroll
        for (int m = 0; m < 8; ++m)
            acc = __builtin_amdgcn_mfma_f32_16x16x32_f16(afrag[m], bfrag[m], acc, 0, 0, 0);

        // ---- cross-wave reduce via LDS (ping-pong, one barrier/step) ----
        const int p = t & 1;
#pragma unroll
        for (int j = 0; j < 4; ++j)
            cred[p][w][kg * 4 + j][ar] = acc[j];
        __syncthreads();

        if (tid < 128) {
            const float s = cred[p][0][ech][eb] + cred[p][1][ech][eb]
                          + cred[p][2][ech][eb] + cred[p][3][ech][eb];
            const float cand = tanhf(s + xw_pref);
            const float hnew = d_pref * hp + (1.0f - d_pref) * cand;
            hp = hnew;
            out[oidx] = hnew;                        // plain cached store (private)
            _Float16 hh = (_Float16)hnew;
            u16 hbits;
            __builtin_memcpy(&hbits, &hh, 2);
            const u32 gran = ((u32)t << 16) | (u32)hbits;
            const u64 dst = (u64)hb + (u64)(t & 1) * (BB * HH * 4)
                          + (u64)(eb * HH + egch) * 4;
            asm volatile("global_store_dword %0, %1, off sc0 sc1"
                         :: "v"(dst), "v"(gran) : "memory");
        }
    }
}

// ---------------- launch ----------------
extern "C" void kernel_launch(void* const* d_in, const int* in_sizes, int n_in,
                              void* d_out, int out_size, void* d_ws, size_t ws_size,
                              hipStream_t stream) {
    const float* x    = (const float*)d_in[0];
    const float* h0   = (const float*)d_in[1];
    const float* Wx   = (const float*)d_in[2];
    const float* R    = (const float*)d_in[3];
    const float* bias = (const float*)d_in[4];
    const float* Wd   = (const float*)d_in[5];
    const float* bdel = (const float*)d_in[6];
    float* out = (float*)d_out;

    float* decay = (float*)d_ws;                                 // 64 MiB
    u32* hb = (u32*)((char*)d_ws + (size_t)TT * BB * HH * 4);    // 2 x 32 KiB ping-pong

    clear_hb_kernel<<<64, 256, 0, stream>>>(hb);
    proj_kernel<<<dim3(HH / BN, (TT * BB) / BM), 256, 0, stream>>>(
        x, Wx, Wd, bias, bdel, out, decay);
    scan_kernel<<<NBLK, 256, 0, stream>>>(h0, R, decay, out, hb);
}

// Round 5
// 4814.204 us; speedup vs baseline: 4.6639x; 2.0766x over previous
//
#include <hip/hip_runtime.h>

#define TT 2048
#define BB 8
#define DD 1024
#define HH 1024
#define NG 8      // blocks per batch group
#define CHB 128   // channels per block

typedef unsigned int u32;
typedef unsigned short u16;
typedef unsigned long long u64;
typedef float f32x4 __attribute__((ext_vector_type(4)));
typedef u32 u32x2 __attribute__((ext_vector_type(2)));
typedef _Float16 f16x8 __attribute__((ext_vector_type(8)));

static __device__ __forceinline__ u16 f16bits(float x) {
    _Float16 h = (_Float16)x;
    u16 r;
    __builtin_memcpy(&r, &h, 2);
    return r;
}

// ---------------- tag invalidation (every launch: no cross-call state) ----------------
__global__ __launch_bounds__(256) void clear_hb_kernel(u32* hb) {
    const int i = blockIdx.x * 256 + threadIdx.x;   // 64 x 256 = 16384 granules
    __hip_atomic_store(&hb[i], 0xFFFF0000u, __ATOMIC_RELAXED, __HIP_MEMORY_SCOPE_AGENT);
}

// ---------------- fused projection GEMMs (unchanged) ----------------
#define BM 128
#define BN 64
#define BK 16

__global__ __launch_bounds__(256) void proj_kernel(
    const float* __restrict__ x, const float* __restrict__ Wx,
    const float* __restrict__ Wd, const float* __restrict__ bias,
    const float* __restrict__ bdel, float* __restrict__ xw_out,
    float* __restrict__ decay_out)
{
    __shared__ float As[BM][BK + 1];
    __shared__ float Bxs[BN][BK + 1];
    __shared__ float Bds[BN][BK + 1];

    const int bm = blockIdx.y * BM;
    const int bn = blockIdx.x * BN;
    const int tid = threadIdx.x;
    const int tx = tid & 15, ty = tid >> 4;

    float accx[8][4] = {};
    float accd[8][4] = {};

    for (int k0 = 0; k0 < DD; k0 += BK) {
#pragma unroll
        for (int l = 0; l < 2; ++l) {
            const int f = tid + l * 256;
            const int row = f >> 2, kc = (f & 3) * 4;
            const float4 v = *(const float4*)&x[(size_t)(bm + row) * DD + k0 + kc];
            As[row][kc + 0] = v.x; As[row][kc + 1] = v.y;
            As[row][kc + 2] = v.z; As[row][kc + 3] = v.w;
        }
        {
            const int row = tid >> 2, kc = (tid & 3) * 4;
            float4 v = *(const float4*)&Wx[(size_t)(bn + row) * DD + k0 + kc];
            Bxs[row][kc + 0] = v.x; Bxs[row][kc + 1] = v.y;
            Bxs[row][kc + 2] = v.z; Bxs[row][kc + 3] = v.w;
            v = *(const float4*)&Wd[(size_t)(bn + row) * DD + k0 + kc];
            Bds[row][kc + 0] = v.x; Bds[row][kc + 1] = v.y;
            Bds[row][kc + 2] = v.z; Bds[row][kc + 3] = v.w;
        }
        __syncthreads();
#pragma unroll
        for (int k = 0; k < BK; ++k) {
            float af[8], bxf[4], bdf[4];
#pragma unroll
            for (int i = 0; i < 8; ++i) af[i] = As[ty * 8 + i][k];
#pragma unroll
            for (int j = 0; j < 4; ++j) { bxf[j] = Bxs[tx * 4 + j][k]; bdf[j] = Bds[tx * 4 + j][k]; }
#pragma unroll
            for (int i = 0; i < 8; ++i)
#pragma unroll
                for (int j = 0; j < 4; ++j) {
                    accx[i][j] += af[i] * bxf[j];
                    accd[i][j] += af[i] * bdf[j];
                }
        }
        __syncthreads();
    }

#pragma unroll
    for (int i = 0; i < 8; ++i) {
        const int row = bm + ty * 8 + i;
        const int col0 = bn + tx * 4;
        float4 xo, dc;
        xo.x = accx[i][0] + bias[col0 + 0];
        xo.y = accx[i][1] + bias[col0 + 1];
        xo.z = accx[i][2] + bias[col0 + 2];
        xo.w = accx[i][3] + bias[col0 + 3];
        dc.x = 1.0f / (1.0f + expf(accd[i][0] + bdel[col0 + 0]));
        dc.y = 1.0f / (1.0f + expf(accd[i][1] + bdel[col0 + 1]));
        dc.z = 1.0f / (1.0f + expf(accd[i][2] + bdel[col0 + 2]));
        dc.w = 1.0f / (1.0f + expf(accd[i][3] + bdel[col0 + 3]));
        *(float4*)&xw_out[(size_t)row * HH + col0] = xo;
        *(float4*)&decay_out[(size_t)row * HH + col0] = dc;
    }
}

// ---------------- sequential scan: batch-split groups + MFMA + tag-in-data ----------------
// 64 blocks x 512 threads (8 waves). Block (b = blkid&7, g = blkid>>3) owns
// channels [g*128, g*128+128) of batch b. The 8 batch chains are independent:
// each group of 8 blocks synchronizes only internally (tail = max over 8).
// Wave w covers K in [w*128, +128): 8 ch-tiles x 4 K-steps of mfma 16x16x32 f16.
// h_{t-1} (1024 fp16) arrives as tagged u32 granules {tag16|fp16}: each thread
// polls ONE dwordx2 (2 granules), unpacks to LDS; own-block channels come from
// the epilogue's direct LDS write (no IF$ round trip). Only col 0 of each MFMA
// C-tile is meaningful (all cols identical: every lane feeds the same h slice).
__global__ __launch_bounds__(512, 2) void scan_kernel(
    const float* __restrict__ h0, const float* __restrict__ R,
    const float* __restrict__ decay, float* __restrict__ out,
    u32* __restrict__ hb)
{
    __shared__ __align__(16) u16 hlds[HH];        // h_{t-1} fp16, 2 KB
    __shared__ __align__(16) float cred[8][CHB];  // per-wave partials, 4 KB

    const int tid = threadIdx.x;
    const int w = tid >> 6;          // wave 0..7 -> K range [w*128, +128)
    const int l = tid & 63;
    const int ar = l & 15;           // A row within 16-ch tile
    const int kg = l >> 4;           // 0..3, k sub-offset kg*8
    const int b = blockIdx.x & 7;    // batch
    const int g = blockIdx.x >> 3;   // channel-group: [g*128, +128)

    // ---- one-time A fragments: R rows -> fp16, 32 frags = 128 VGPRs ----
    f16x8 afrag[8][4];
#pragma unroll
    for (int c = 0; c < 8; ++c)
#pragma unroll
        for (int s = 0; s < 4; ++s) {
            const float* rp = &R[(size_t)(g * CHB + c * 16 + ar) * HH
                                 + w * 128 + s * 32 + kg * 8];
            const f32x4 r0 = *(const f32x4*)rp;
            const f32x4 r1 = *(const f32x4*)(rp + 4);
            f16x8 a;
            a[0] = (_Float16)r0.x; a[1] = (_Float16)r0.y;
            a[2] = (_Float16)r0.z; a[3] = (_Float16)r0.w;
            a[4] = (_Float16)r1.x; a[5] = (_Float16)r1.y;
            a[6] = (_Float16)r1.z; a[7] = (_Float16)r1.w;
            afrag[c][s] = a;
        }

    // previous own-h kept in register (epilogue threads only)
    float hp = 0.f;
    if (tid < CHB) hp = h0[(size_t)b * HH + g * CHB + tid];

    for (int t = 0; t < TT; ++t) {
        // ---- prefetch own xw/decay (race-free, cached) ----
        float xw_pref = 0.f, d_pref = 0.f;
        size_t oidx = 0;
        if (tid < CHB) {
            oidx = (size_t)t * (BB * HH) + (size_t)b * HH + g * CHB + tid;
            xw_pref = out[oidx];       // projection value, still intact
            d_pref = decay[oidx];
        }

        // ---- stage h_{t-1}: one dwordx2 (2 tagged granules) per thread ----
        if (t == 0) {
            const float2 v = *(const float2*)&h0[(size_t)b * HH + tid * 2];
            const u32 packed = (u32)f16bits(v.x) | ((u32)f16bits(v.y) << 16);
            *(u32*)&hlds[tid * 2] = packed;
        } else if ((tid >> 6) != g) {   // own 128 channels come via LDS from epilogue
            const u32 tagv = (u32)(t - 1);
            const u64 gptr = (u64)hb
                           + (u64)(((t - 1) & 1) * (BB * HH) + b * HH + tid * 2) * 4;
            u32x2 gg;
            do {
                asm volatile("global_load_dwordx2 %0, %1, off sc0 sc1"
                             : "=v"(gg) : "v"(gptr));
                asm volatile("s_waitcnt vmcnt(0)" ::: "memory");
                __builtin_amdgcn_sched_barrier(0);
            } while ((gg[0] >> 16) != tagv || (gg[1] >> 16) != tagv);
            *(u32*)&hlds[tid * 2] = (gg[0] & 0xffffu) | (gg[1] << 16);
        }
        __syncthreads();

        // ---- 32 MFMAs: C[128ch x col0] over this wave's K range ----
        f32x4 acc[8];
#pragma unroll
        for (int c = 0; c < 8; ++c) acc[c] = (f32x4){0.f, 0.f, 0.f, 0.f};
#pragma unroll
        for (int s = 0; s < 4; ++s) {
            const f16x8 bfrag = *(const f16x8*)&hlds[w * 128 + s * 32 + kg * 8];
#pragma unroll
            for (int c = 0; c < 8; ++c)
                acc[c] = __builtin_amdgcn_mfma_f32_16x16x32_f16(
                             afrag[c][s], bfrag, acc[c], 0, 0, 0);
        }
        // all C-cols are identical; lanes with ar==0 hold rows kg*4..kg*4+3
        if (ar == 0) {
#pragma unroll
            for (int c = 0; c < 8; ++c)
                *(f32x4*)&cred[w][c * 16 + kg * 4] = acc[c];
        }
        __syncthreads();

        // ---- final combine + pointwise + broadcast ----
        if (tid < CHB) {
            float s = cred[0][tid] + cred[1][tid] + cred[2][tid] + cred[3][tid]
                    + cred[4][tid] + cred[5][tid] + cred[6][tid] + cred[7][tid];
            const float cand = tanhf(s + xw_pref);
            const float hnew = d_pref * hp + (1.0f - d_pref) * cand;
            hp = hnew;
            out[oidx] = hnew;                       // private range, plain store
            const u16 hbits = f16bits(hnew);
            const u32 gran = ((u32)t << 16) | (u32)hbits;
            const u64 dst = (u64)hb
                          + (u64)((t & 1) * (BB * HH) + b * HH + g * CHB + tid) * 4;
            asm volatile("global_store_dword %0, %1, off sc0 sc1"
                         :: "v"(dst), "v"(gran) : "memory");
            hlds[g * CHB + tid] = hbits;            // own range for next step
        }
    }
}

// ---------------- launch ----------------
extern "C" void kernel_launch(void* const* d_in, const int* in_sizes, int n_in,
                              void* d_out, int out_size, void* d_ws, size_t ws_size,
                              hipStream_t stream) {
    const float* x    = (const float*)d_in[0];
    const float* h0   = (const float*)d_in[1];
    const float* Wx   = (const float*)d_in[2];
    const float* R    = (const float*)d_in[3];
    const float* bias = (const float*)d_in[4];
    const float* Wd   = (const float*)d_in[5];
    const float* bdel = (const float*)d_in[6];
    float* out = (float*)d_out;

    float* decay = (float*)d_ws;                                 // 64 MiB
    u32* hb = (u32*)((char*)d_ws + (size_t)TT * BB * HH * 4);    // 2 x 32 KiB ping-pong

    clear_hb_kernel<<<64, 256, 0, stream>>>(hb);
    proj_kernel<<<dim3(HH / BN, (TT * BB) / BM), 256, 0, stream>>>(
        x, Wx, Wd, bias, bdel, out, decay);
    scan_kernel<<<64, 512, 0, stream>>>(h0, R, decay, out, hb);
}

// Round 6
// 4716.873 us; speedup vs baseline: 4.7601x; 1.0206x over previous
//
#include <hip/hip_runtime.h>

#define TT 2048
#define BB 8
#define DD 1024
#define HH 1024
#define CHB 128   // channels per block

typedef unsigned int u32;
typedef unsigned short u16;
typedef unsigned long long u64;
typedef float f32x4 __attribute__((ext_vector_type(4)));
typedef u32 u32x4 __attribute__((ext_vector_type(4)));
typedef _Float16 f16x8 __attribute__((ext_vector_type(8)));

static __device__ __forceinline__ u16 f16bits(float x) {
    _Float16 h = (_Float16)x;
    u16 r;
    __builtin_memcpy(&r, &h, 2);
    return r;
}

// ---------------- tag invalidation (every launch: no cross-call state) ----------------
__global__ __launch_bounds__(256) void clear_hb_kernel(u32* hb) {
    const int i = blockIdx.x * 256 + threadIdx.x;   // 64 x 256 = 16384 granules
    __hip_atomic_store(&hb[i], 0xFFFF0000u, __ATOMIC_RELAXED, __HIP_MEMORY_SCOPE_AGENT);
}

// ---------------- fused projection GEMMs via MFMA fp16 ----------------
// C[r][h] = sum_k x[r][k] * W[h][k]  for W in {Wx, Wd}; shared A-tile (x).
// 64x64 tile, 4 waves, wave w owns rows [w*16,+16); 4 col-tiles of 16.
__global__ __launch_bounds__(256) void proj_kernel(
    const float* __restrict__ x, const float* __restrict__ Wx,
    const float* __restrict__ Wd, const float* __restrict__ bias,
    const float* __restrict__ bdel, float* __restrict__ xw_out,
    float* __restrict__ decay_out)
{
    __shared__ __align__(16) _Float16 xs[64][40];
    __shared__ __align__(16) _Float16 wxs[64][40];
    __shared__ __align__(16) _Float16 wds[64][40];

    const int tid = threadIdx.x;
    const int bm = blockIdx.y * 64;
    const int bn = blockIdx.x * 64;
    const int w = tid >> 6, l = tid & 63;
    const int ar = l & 15, kg = l >> 4;
    const int srow = tid >> 2, scol = (tid & 3) * 8;   // staging: row, k-offset

    f32x4 accx[4], accd[4];
#pragma unroll
    for (int ct = 0; ct < 4; ++ct) {
        accx[ct] = (f32x4){0.f, 0.f, 0.f, 0.f};
        accd[ct] = (f32x4){0.f, 0.f, 0.f, 0.f};
    }

    for (int k0 = 0; k0 < DD; k0 += 32) {
        // global loads (fp32) -> fp16 regs
        const float* xp = &x[(size_t)(bm + srow) * DD + k0 + scol];
        const float* wxp = &Wx[(size_t)(bn + srow) * DD + k0 + scol];
        const float* wdp = &Wd[(size_t)(bn + srow) * DD + k0 + scol];
        f32x4 a0 = *(const f32x4*)xp,  a1 = *(const f32x4*)(xp + 4);
        f32x4 b0 = *(const f32x4*)wxp, b1 = *(const f32x4*)(wxp + 4);
        f32x4 c0 = *(const f32x4*)wdp, c1 = *(const f32x4*)(wdp + 4);
        f16x8 ha, hb_, hc;
#pragma unroll
        for (int e = 0; e < 4; ++e) {
            ha[e] = (_Float16)a0[e];  ha[e + 4] = (_Float16)a1[e];
            hb_[e] = (_Float16)b0[e]; hb_[e + 4] = (_Float16)b1[e];
            hc[e] = (_Float16)c0[e];  hc[e + 4] = (_Float16)c1[e];
        }
        __syncthreads();   // previous iter's LDS reads complete
        *(f16x8*)&xs[srow][scol] = ha;
        *(f16x8*)&wxs[srow][scol] = hb_;
        *(f16x8*)&wds[srow][scol] = hc;
        __syncthreads();

        const f16x8 af = *(const f16x8*)&xs[w * 16 + ar][kg * 8];
#pragma unroll
        for (int ct = 0; ct < 4; ++ct) {
            const f16x8 bfx = *(const f16x8*)&wxs[ct * 16 + ar][kg * 8];
            const f16x8 bfd = *(const f16x8*)&wds[ct * 16 + ar][kg * 8];
            accx[ct] = __builtin_amdgcn_mfma_f32_16x16x32_f16(af, bfx, accx[ct], 0, 0, 0);
            accd[ct] = __builtin_amdgcn_mfma_f32_16x16x32_f16(af, bfd, accd[ct], 0, 0, 0);
        }
    }

    // epilogue: C row = bm + w*16 + kg*4 + j, col = bn + ct*16 + ar
#pragma unroll
    for (int ct = 0; ct < 4; ++ct) {
        const int col = bn + ct * 16 + ar;
        const float bx = bias[col];
        const float bd = bdel[col];
#pragma unroll
        for (int j = 0; j < 4; ++j) {
            const int row = bm + w * 16 + kg * 4 + j;
            xw_out[(size_t)row * HH + col] = accx[ct][j] + bx;
            decay_out[(size_t)row * HH + col] = 1.0f / (1.0f + expf(accd[ct][j] + bd));
        }
    }
}

// ---------------- sequential scan: barrier-free, wave-owns-channels ----------------
// 64 blocks x 512 threads (8 waves). Block (b=blk&7, g=blk>>3) owns channels
// [g*128,+128) of batch b. Wave w owns 16 channels x FULL K=1024: its MFMA acc
// is the complete dot product -> no cross-wave reduce, NO __syncthreads in the
// t-loop. Each wave polls its own full-h copy (tagged granules {tag16|fp16}),
// unpacks into a private LDS strip (wave-local => lgkmcnt ordering only).
// Ping-pong safety: wave stores tag t only after polling all of t-1 complete,
// so tag-t-complete implies nobody still reads t-2 (per-granule induction).
__global__ __launch_bounds__(512) void scan_kernel(
    const float* __restrict__ h0, const float* __restrict__ R,
    const float* __restrict__ decay, float* __restrict__ out,
    u32* __restrict__ hb)
{
    __shared__ __align__(16) _Float16 hw[8][HH];   // per-wave h copy, 16 KB

    const int tid = threadIdx.x;
    const int w = tid >> 6;
    const int l = tid & 63;
    const int ar = l & 15, kg = l >> 4;
    const int b = blockIdx.x & 7, g = blockIdx.x >> 3;

    // ---- one-time A fragments: R row (one channel) x full K, 128 VGPRs ----
    const int chrow = g * CHB + w * 16 + ar;
    f16x8 afrag[32];
#pragma unroll
    for (int s = 0; s < 32; ++s) {
        const float* rp = &R[(size_t)chrow * HH + s * 32 + kg * 8];
        const f32x4 r0 = *(const f32x4*)rp;
        const f32x4 r1 = *(const f32x4*)(rp + 4);
        f16x8 a;
#pragma unroll
        for (int e = 0; e < 4; ++e) { a[e] = (_Float16)r0[e]; a[e + 4] = (_Float16)r1[e]; }
        afrag[s] = a;
    }

    // epilogue lanes: ar<4 handle channel kg*4+ar via acc component ar
    const bool ep = (ar < 4);
    const int ch = g * CHB + w * 16 + kg * 4 + ar;   // valid when ep
    float hp = 0.f, xw_c = 0.f, d_c = 0.f;
    if (ep) {
        hp = h0[(size_t)b * HH + ch];
        xw_c = out[(size_t)b * HH + ch];     // row 0 projection
        d_c = decay[(size_t)b * HH + ch];
    }

    for (int t = 0; t < TT; ++t) {
        // ---- stage h_{t-1} into this wave's private LDS strip ----
        if (t == 0) {
            const float* hsp = &h0[(size_t)b * HH + l * 16];
            const f32x4 v0 = *(const f32x4*)hsp;
            const f32x4 v1 = *(const f32x4*)(hsp + 4);
            const f32x4 v2 = *(const f32x4*)(hsp + 8);
            const f32x4 v3 = *(const f32x4*)(hsp + 12);
            f16x8 h0a, h0b;
#pragma unroll
            for (int e = 0; e < 4; ++e) {
                h0a[e] = (_Float16)v0[e]; h0a[e + 4] = (_Float16)v1[e];
                h0b[e] = (_Float16)v2[e]; h0b[e + 4] = (_Float16)v3[e];
            }
            *(f16x8*)&hw[w][l * 16] = h0a;
            *(f16x8*)&hw[w][l * 16 + 8] = h0b;
        } else {
            const u32 expt = (u32)(t - 1) << 16;
            const u64 gp = (u64)hb + (u64)(((t - 1) & 1) * (BB * HH) + b * HH + l * 16) * 4;
            u32x4 q0, q1, q2, q3;
            while (true) {
                asm volatile(
                    "global_load_dwordx4 %0, %4, off sc0 sc1\n\t"
                    "global_load_dwordx4 %1, %4, off offset:16 sc0 sc1\n\t"
                    "global_load_dwordx4 %2, %4, off offset:32 sc0 sc1\n\t"
                    "global_load_dwordx4 %3, %4, off offset:48 sc0 sc1\n\t"
                    "s_waitcnt vmcnt(0)"
                    : "=&v"(q0), "=&v"(q1), "=&v"(q2), "=&v"(q3)
                    : "v"(gp) : "memory");
                __builtin_amdgcn_sched_barrier(0);
                const u32 m = (q0[0] ^ expt) | (q0[1] ^ expt) | (q0[2] ^ expt) | (q0[3] ^ expt)
                            | (q1[0] ^ expt) | (q1[1] ^ expt) | (q1[2] ^ expt) | (q1[3] ^ expt)
                            | (q2[0] ^ expt) | (q2[1] ^ expt) | (q2[2] ^ expt) | (q2[3] ^ expt)
                            | (q3[0] ^ expt) | (q3[1] ^ expt) | (q3[2] ^ expt) | (q3[3] ^ expt);
                if (!(m & 0xffff0000u)) break;
            }
            u32x4 P0, P1;
            P0[0] = (q0[0] & 0xffffu) | (q0[1] << 16);
            P0[1] = (q0[2] & 0xffffu) | (q0[3] << 16);
            P0[2] = (q1[0] & 0xffffu) | (q1[1] << 16);
            P0[3] = (q1[2] & 0xffffu) | (q1[3] << 16);
            P1[0] = (q2[0] & 0xffffu) | (q2[1] << 16);
            P1[1] = (q2[2] & 0xffffu) | (q2[3] << 16);
            P1[2] = (q3[0] & 0xffffu) | (q3[1] << 16);
            P1[3] = (q3[2] & 0xffffu) | (q3[3] << 16);
            *(u32x4*)&hw[w][l * 16] = P0;
            *(u32x4*)&hw[w][l * 16 + 8] = P1;
        }

        // ---- prefetch NEXT step's xw/decay (latency hides under this step) ----
        float xw_n = xw_c, d_n = d_c;
        if (ep && t + 1 < TT) {
            const size_t nidx = (size_t)(t + 1) * (BB * HH) + (size_t)b * HH + ch;
            xw_n = out[nidx];
            d_n = decay[nidx];
        }

        // ---- 32 MFMAs (full K), 4 interleaved chains ----
        f32x4 ac0 = {0.f, 0.f, 0.f, 0.f}, ac1 = ac0, ac2 = ac0, ac3 = ac0;
#pragma unroll
        for (int s = 0; s < 32; s += 4) {
            ac0 = __builtin_amdgcn_mfma_f32_16x16x32_f16(
                      afrag[s + 0], *(const f16x8*)&hw[w][(s + 0) * 32 + kg * 8], ac0, 0, 0, 0);
            ac1 = __builtin_amdgcn_mfma_f32_16x16x32_f16(
                      afrag[s + 1], *(const f16x8*)&hw[w][(s + 1) * 32 + kg * 8], ac1, 0, 0, 0);
            ac2 = __builtin_amdgcn_mfma_f32_16x16x32_f16(
                      afrag[s + 2], *(const f16x8*)&hw[w][(s + 2) * 32 + kg * 8], ac2, 0, 0, 0);
            ac3 = __builtin_amdgcn_mfma_f32_16x16x32_f16(
                      afrag[s + 3], *(const f16x8*)&hw[w][(s + 3) * 32 + kg * 8], ac3, 0, 0, 0);
        }
        const f32x4 acc = (ac0 + ac1) + (ac2 + ac3);

        // ---- epilogue: 16 lanes/wave, complete sums, tagged broadcast ----
        if (ep) {
            const float s = (ar == 0) ? acc[0] : (ar == 1) ? acc[1]
                          : (ar == 2) ? acc[2] : acc[3];
            const float cand = tanhf(s + xw_c);
            const float hnew = d_c * hp + (1.0f - d_c) * cand;
            hp = hnew;
            out[(size_t)t * (BB * HH) + (size_t)b * HH + ch] = hnew;
            const u32 gran = ((u32)t << 16) | (u32)f16bits(hnew);
            const u64 dst = (u64)hb + (u64)((t & 1) * (BB * HH) + b * HH + ch) * 4;
            asm volatile("global_store_dword %0, %1, off sc0 sc1"
                         :: "v"(dst), "v"(gran) : "memory");
        }
        xw_c = xw_n;
        d_c = d_n;
    }
}

// ---------------- launch ----------------
extern "C" void kernel_launch(void* const* d_in, const int* in_sizes, int n_in,
                              void* d_out, int out_size, void* d_ws, size_t ws_size,
                              hipStream_t stream) {
    const float* x    = (const float*)d_in[0];
    const float* h0   = (const float*)d_in[1];
    const float* Wx   = (const float*)d_in[2];
    const float* R    = (const float*)d_in[3];
    const float* bias = (const float*)d_in[4];
    const float* Wd   = (const float*)d_in[5];
    const float* bdel = (const float*)d_in[6];
    float* out = (float*)d_out;

    float* decay = (float*)d_ws;                                 // 64 MiB
    u32* hb = (u32*)((char*)d_ws + (size_t)TT * BB * HH * 4);    // 2 x 32 KiB ping-pong

    clear_hb_kernel<<<64, 256, 0, stream>>>(hb);
    proj_kernel<<<dim3(HH / 64, (TT * BB) / 64), 256, 0, stream>>>(
        x, Wx, Wd, bias, bdel, out, decay);
    scan_kernel<<<64, 512, 0, stream>>>(h0, R, decay, out, hb);
}

// Round 7
// 3380.012 us; speedup vs baseline: 6.6428x; 1.3955x over previous
//
#include <hip/hip_runtime.h>

#define TT 2048
#define BB 8
#define DD 1024
#define HH 1024
#define CHB 128   // channels per block

typedef unsigned int u32;
typedef unsigned short u16;
typedef unsigned long long u64;
typedef float f32x4 __attribute__((ext_vector_type(4)));
typedef u32 u32x2 __attribute__((ext_vector_type(2)));
typedef _Float16 f16x8 __attribute__((ext_vector_type(8)));

static __device__ __forceinline__ u16 f16bits(float x) {
    _Float16 h = (_Float16)x;
    u16 r;
    __builtin_memcpy(&r, &h, 2);
    return r;
}

// ---------------- tag invalidation (every launch: no cross-call state) ----------------
__global__ __launch_bounds__(256) void clear_hb_kernel(u32* hb) {
    const int i = blockIdx.x * 256 + threadIdx.x;   // 64 x 256 = 16384 granules
    __hip_atomic_store(&hb[i], 0xFFFF0000u, __ATOMIC_RELAXED, __HIP_MEMORY_SCOPE_AGENT);
}

// ---------------- fused projection GEMMs via MFMA fp16 (unchanged from R6) ----------------
__global__ __launch_bounds__(256) void proj_kernel(
    const float* __restrict__ x, const float* __restrict__ Wx,
    const float* __restrict__ Wd, const float* __restrict__ bias,
    const float* __restrict__ bdel, float* __restrict__ xw_out,
    float* __restrict__ decay_out)
{
    __shared__ __align__(16) _Float16 xs[64][40];
    __shared__ __align__(16) _Float16 wxs[64][40];
    __shared__ __align__(16) _Float16 wds[64][40];

    const int tid = threadIdx.x;
    const int bm = blockIdx.y * 64;
    const int bn = blockIdx.x * 64;
    const int w = tid >> 6, l = tid & 63;
    const int ar = l & 15, kg = l >> 4;
    const int srow = tid >> 2, scol = (tid & 3) * 8;

    f32x4 accx[4], accd[4];
#pragma unroll
    for (int ct = 0; ct < 4; ++ct) {
        accx[ct] = (f32x4){0.f, 0.f, 0.f, 0.f};
        accd[ct] = (f32x4){0.f, 0.f, 0.f, 0.f};
    }

    for (int k0 = 0; k0 < DD; k0 += 32) {
        const float* xp = &x[(size_t)(bm + srow) * DD + k0 + scol];
        const float* wxp = &Wx[(size_t)(bn + srow) * DD + k0 + scol];
        const float* wdp = &Wd[(size_t)(bn + srow) * DD + k0 + scol];
        f32x4 a0 = *(const f32x4*)xp,  a1 = *(const f32x4*)(xp + 4);
        f32x4 b0 = *(const f32x4*)wxp, b1 = *(const f32x4*)(wxp + 4);
        f32x4 c0 = *(const f32x4*)wdp, c1 = *(const f32x4*)(wdp + 4);
        f16x8 ha, hb_, hc;
#pragma unroll
        for (int e = 0; e < 4; ++e) {
            ha[e] = (_Float16)a0[e];  ha[e + 4] = (_Float16)a1[e];
            hb_[e] = (_Float16)b0[e]; hb_[e + 4] = (_Float16)b1[e];
            hc[e] = (_Float16)c0[e];  hc[e + 4] = (_Float16)c1[e];
        }
        __syncthreads();
        *(f16x8*)&xs[srow][scol] = ha;
        *(f16x8*)&wxs[srow][scol] = hb_;
        *(f16x8*)&wds[srow][scol] = hc;
        __syncthreads();

        const f16x8 af = *(const f16x8*)&xs[w * 16 + ar][kg * 8];
#pragma unroll
        for (int ct = 0; ct < 4; ++ct) {
            const f16x8 bfx = *(const f16x8*)&wxs[ct * 16 + ar][kg * 8];
            const f16x8 bfd = *(const f16x8*)&wds[ct * 16 + ar][kg * 8];
            accx[ct] = __builtin_amdgcn_mfma_f32_16x16x32_f16(af, bfx, accx[ct], 0, 0, 0);
            accd[ct] = __builtin_amdgcn_mfma_f32_16x16x32_f16(af, bfd, accd[ct], 0, 0, 0);
        }
    }

#pragma unroll
    for (int ct = 0; ct < 4; ++ct) {
        const int col = bn + ct * 16 + ar;
        const float bx = bias[col];
        const float bd = bdel[col];
#pragma unroll
        for (int j = 0; j < 4; ++j) {
            const int row = bm + w * 16 + kg * 4 + j;
            xw_out[(size_t)row * HH + col] = accx[ct][j] + bx;
            decay_out[(size_t)row * HH + col] = 1.0f / (1.0f + expf(accd[ct][j] + bd));
        }
    }
}

// ---------------- sequential scan: shared strip + single barrier + no reduce ----------------
// 64 blocks x 512 threads (8 waves). Block (b=blk&7, g=blk>>3) owns channels
// [g*128,+128) of batch b; groups of 8 blocks per batch self-pace (tail=max-of-8).
// ONE shared h strip per step (ping-pong hst[2][1024]): each non-own thread polls
// one tagged dwordx2 {tag16|fp16} and writes 4B contiguous to LDS (conflict-free);
// own 128 channels short-circuit via the previous epilogue's LDS write.
// Single __syncthreads per step (after poll, before MFMA). Wave w owns 16 channels
// x full K=1024 -> accumulator holds the complete dot; no cross-wave reduce.
// Protocol: block stores tag t only after block-wide poll of t-1 (barrier) =>
// ping-pong overwrite of tag t-2 is race-free (same induction as R5/R6).
__global__ __launch_bounds__(512) void scan_kernel(
    const float* __restrict__ h0, const float* __restrict__ R,
    const float* __restrict__ decay, float* __restrict__ out,
    u32* __restrict__ hb)
{
    __shared__ __align__(16) _Float16 hst[2][HH];   // ping-pong strip, 4 KB

    const int tid = threadIdx.x;
    const int w = tid >> 6;
    const int l = tid & 63;
    const int ar = l & 15, kg = l >> 4;
    const int b = blockIdx.x & 7, g = blockIdx.x >> 3;

    // ---- one-time A fragments: R row (one channel) x full K, 128 VGPRs ----
    const int chrow = g * CHB + w * 16 + ar;
    f16x8 afrag[32];
#pragma unroll
    for (int s = 0; s < 32; ++s) {
        const float* rp = &R[(size_t)chrow * HH + s * 32 + kg * 8];
        const f32x4 r0 = *(const f32x4*)rp;
        const f32x4 r1 = *(const f32x4*)(rp + 4);
        f16x8 a;
#pragma unroll
        for (int e = 0; e < 4; ++e) { a[e] = (_Float16)r0[e]; a[e + 4] = (_Float16)r1[e]; }
        afrag[s] = a;
    }

    // thread's poll coverage: granules {2tid, 2tid+1}; own range <-> tid>>6 == g
    const bool pollme = ((tid >> 6) != g);

    // epilogue lanes: ar<4 handle channel w*16 + kg*4 + ar via acc component ar
    const bool ep = (ar < 4);
    const int ch = g * CHB + w * 16 + kg * 4 + ar;     // valid when ep
    const int chloc = w * 16 + kg * 4 + ar;            // channel within block
    float hp = 0.f, xw_c = 0.f, d_c = 0.f;
    if (ep) {
        hp = h0[(size_t)b * HH + ch];
        xw_c = out[(size_t)b * HH + ch];     // row 0 projection (still intact)
        d_c = decay[(size_t)b * HH + ch];
    }

    for (int t = 0; t < TT; ++t) {
        const int p = t & 1;
        // ---- fill strip p: poll remote granules (or h0 at t==0) ----
        if (t == 0) {
            const float2 v = *(const float2*)&h0[(size_t)b * HH + tid * 2];
            *(u32*)&hst[0][tid * 2] = (u32)f16bits(v.x) | ((u32)f16bits(v.y) << 16);
        } else if (pollme) {
            const u32 expt = (u32)(t - 1) << 16;
            const u64 gp = (u64)hb
                         + (u64)(((t - 1) & 1) * (BB * HH) + b * HH + tid * 2) * 4;
            u32x2 gg;
            while (true) {
                asm volatile(
                    "global_load_dwordx2 %0, %1, off sc0 sc1\n\t"
                    "s_waitcnt vmcnt(0)"
                    : "=&v"(gg) : "v"(gp) : "memory");
                __builtin_amdgcn_sched_barrier(0);
                const u32 m = (gg[0] ^ expt) | (gg[1] ^ expt);
                if (!(m & 0xffff0000u)) break;
            }
            *(u32*)&hst[p][tid * 2] = (gg[0] & 0xffffu) | (gg[1] << 16);
        }
        __syncthreads();   // strip p complete (poll writes + prev epilogue's own-range)

        // ---- prefetch NEXT step's xw/decay (hides under this step) ----
        float xw_n = xw_c, d_n = d_c;
        if (ep && t + 1 < TT) {
            const size_t nidx = (size_t)(t + 1) * (BB * HH) + (size_t)b * HH + ch;
            xw_n = out[nidx];
            d_n = decay[nidx];
        }

        // ---- 32 MFMAs (full K), 4 interleaved chains, B-frags from shared strip ----
        f32x4 ac0 = {0.f, 0.f, 0.f, 0.f}, ac1 = ac0, ac2 = ac0, ac3 = ac0;
#pragma unroll
        for (int s = 0; s < 32; s += 4) {
            ac0 = __builtin_amdgcn_mfma_f32_16x16x32_f16(
                      afrag[s + 0], *(const f16x8*)&hst[p][(s + 0) * 32 + kg * 8], ac0, 0, 0, 0);
            ac1 = __builtin_amdgcn_mfma_f32_16x16x32_f16(
                      afrag[s + 1], *(const f16x8*)&hst[p][(s + 1) * 32 + kg * 8], ac1, 0, 0, 0);
            ac2 = __builtin_amdgcn_mfma_f32_16x16x32_f16(
                      afrag[s + 2], *(const f16x8*)&hst[p][(s + 2) * 32 + kg * 8], ac2, 0, 0, 0);
            ac3 = __builtin_amdgcn_mfma_f32_16x16x32_f16(
                      afrag[s + 3], *(const f16x8*)&hst[p][(s + 3) * 32 + kg * 8], ac3, 0, 0, 0);
        }
        const f32x4 acc = (ac0 + ac1) + (ac2 + ac3);

        // ---- epilogue: 16 lanes/wave; write own-range of NEXT strip + broadcast ----
        if (ep) {
            const float s = (ar == 0) ? acc[0] : (ar == 1) ? acc[1]
                          : (ar == 2) ? acc[2] : acc[3];
            const float cand = tanhf(s + xw_c);
            const float hnew = d_c * hp + (1.0f - d_c) * cand;
            hp = hnew;
            out[(size_t)t * (BB * HH) + (size_t)b * HH + ch] = hnew;
            const u16 hbits = f16bits(hnew);
            hst[p ^ 1][g * CHB + chloc] = *(const _Float16*)&hbits;  // own-range shortcut
            const u32 gran = ((u32)t << 16) | (u32)hbits;
            const u64 dst = (u64)hb + (u64)((t & 1) * (BB * HH) + b * HH + ch) * 4;
            asm volatile("global_store_dword %0, %1, off sc0 sc1"
                         :: "v"(dst), "v"(gran) : "memory");
        }
        xw_c = xw_n;
        d_c = d_n;
    }
}

// ---------------- launch ----------------
extern "C" void kernel_launch(void* const* d_in, const int* in_sizes, int n_in,
                              void* d_out, int out_size, void* d_ws, size_t ws_size,
                              hipStream_t stream) {
    const float* x    = (const float*)d_in[0];
    const float* h0   = (const float*)d_in[1];
    const float* Wx   = (const float*)d_in[2];
    const float* R    = (const float*)d_in[3];
    const float* bias = (const float*)d_in[4];
    const float* Wd   = (const float*)d_in[5];
    const float* bdel = (const float*)d_in[6];
    float* out = (float*)d_out;

    float* decay = (float*)d_ws;                                 // 64 MiB
    u32* hb = (u32*)((char*)d_ws + (size_t)TT * BB * HH * 4);    // 2 x 32 KiB ping-pong

    clear_hb_kernel<<<64, 256, 0, stream>>>(hb);
    proj_kernel<<<dim3(HH / 64, (TT * BB) / 64), 256, 0, stream>>>(
        x, Wx, Wd, bias, bdel, out, decay);
    scan_kernel<<<64, 512, 0, stream>>>(h0, R, decay, out, hb);
}

// Round 8
// 3295.108 us; speedup vs baseline: 6.8140x; 1.0258x over previous
//
#include <hip/hip_runtime.h>

#define TT 2048
#define BB 8
#define DD 1024
#define HH 1024
#define CHB 128   // channels per block

typedef unsigned int u32;
typedef unsigned short u16;
typedef unsigned long long u64;
typedef float f32x4 __attribute__((ext_vector_type(4)));
typedef u32 u32x2 __attribute__((ext_vector_type(2)));
typedef _Float16 f16x8 __attribute__((ext_vector_type(8)));

static __device__ __forceinline__ u16 f16bits(float x) {
    _Float16 h = (_Float16)x;
    u16 r;
    __builtin_memcpy(&r, &h, 2);
    return r;
}

// fast tanh: tanh(x) = sign(x) * (1 - e^{-2|x|}) / (1 + e^{-2|x|}), exp2-based
static __device__ __forceinline__ float fast_tanh(float x) {
    const float ax = __builtin_fabsf(x);
    const float e = __builtin_amdgcn_exp2f(ax * -2.885390082f);   // 2^(-2|x|*log2e)
    const float r = (1.0f - e) * __builtin_amdgcn_rcpf(1.0f + e);
    return __builtin_copysignf(r, x);
}

// ---------------- tag invalidation (every launch: no cross-call state) ----------------
__global__ __launch_bounds__(256) void clear_hb_kernel(u32* hb) {
    const int i = blockIdx.x * 256 + threadIdx.x;   // 64 x 256 = 16384 granules
    __hip_atomic_store(&hb[i], 0xFFFF0000u, __ATOMIC_RELAXED, __HIP_MEMORY_SCOPE_AGENT);
}

// ---------------- fused projection GEMMs via MFMA fp16 ----------------
__global__ __launch_bounds__(256) void proj_kernel(
    const float* __restrict__ x, const float* __restrict__ Wx,
    const float* __restrict__ Wd, const float* __restrict__ bias,
    const float* __restrict__ bdel, float* __restrict__ xw_out,
    float* __restrict__ decay_out)
{
    __shared__ __align__(16) _Float16 xs[64][40];
    __shared__ __align__(16) _Float16 wxs[64][40];
    __shared__ __align__(16) _Float16 wds[64][40];

    const int tid = threadIdx.x;
    const int bm = blockIdx.y * 64;
    const int bn = blockIdx.x * 64;
    const int w = tid >> 6, l = tid & 63;
    const int ar = l & 15, kg = l >> 4;
    const int srow = tid >> 2, scol = (tid & 3) * 8;

    f32x4 accx[4], accd[4];
#pragma unroll
    for (int ct = 0; ct < 4; ++ct) {
        accx[ct] = (f32x4){0.f, 0.f, 0.f, 0.f};
        accd[ct] = (f32x4){0.f, 0.f, 0.f, 0.f};
    }

    for (int k0 = 0; k0 < DD; k0 += 32) {
        const float* xp = &x[(size_t)(bm + srow) * DD + k0 + scol];
        const float* wxp = &Wx[(size_t)(bn + srow) * DD + k0 + scol];
        const float* wdp = &Wd[(size_t)(bn + srow) * DD + k0 + scol];
        f32x4 a0 = *(const f32x4*)xp,  a1 = *(const f32x4*)(xp + 4);
        f32x4 b0 = *(const f32x4*)wxp, b1 = *(const f32x4*)(wxp + 4);
        f32x4 c0 = *(const f32x4*)wdp, c1 = *(const f32x4*)(wdp + 4);
        f16x8 ha, hb_, hc;
#pragma unroll
        for (int e = 0; e < 4; ++e) {
            ha[e] = (_Float16)a0[e];  ha[e + 4] = (_Float16)a1[e];
            hb_[e] = (_Float16)b0[e]; hb_[e + 4] = (_Float16)b1[e];
            hc[e] = (_Float16)c0[e];  hc[e + 4] = (_Float16)c1[e];
        }
        __syncthreads();
        *(f16x8*)&xs[srow][scol] = ha;
        *(f16x8*)&wxs[srow][scol] = hb_;
        *(f16x8*)&wds[srow][scol] = hc;
        __syncthreads();

        const f16x8 af = *(const f16x8*)&xs[w * 16 + ar][kg * 8];
#pragma unroll
        for (int ct = 0; ct < 4; ++ct) {
            const f16x8 bfx = *(const f16x8*)&wxs[ct * 16 + ar][kg * 8];
            const f16x8 bfd = *(const f16x8*)&wds[ct * 16 + ar][kg * 8];
            accx[ct] = __builtin_amdgcn_mfma_f32_16x16x32_f16(af, bfx, accx[ct], 0, 0, 0);
            accd[ct] = __builtin_amdgcn_mfma_f32_16x16x32_f16(af, bfd, accd[ct], 0, 0, 0);
        }
    }

#pragma unroll
    for (int ct = 0; ct < 4; ++ct) {
        const int col = bn + ct * 16 + ar;
        const float bx = bias[col];
        const float bd = bdel[col];
#pragma unroll
        for (int j = 0; j < 4; ++j) {
            const int row = bm + w * 16 + kg * 4 + j;
            xw_out[(size_t)row * HH + col] = accx[ct][j] + bx;
            decay_out[(size_t)row * HH + col] = 1.0f / (1.0f + expf(accd[ct][j] + bd));
        }
    }
}

// ---------------- sequential scan: shared strip, staggered double-poll ----------------
// 64 blocks x 512 threads (8 waves). Block (b=blk&7, g=blk>>3) owns channels
// [g*128,+128) of batch b. One shared h strip per step (ping-pong hst[2][1024]);
// non-own threads poll one tagged dwordx2 {tag16|fp16} with TWO staggered
// outstanding loads (sampling period ~L/2); own range short-circuits via LDS.
// Single __syncthreads per step. Wave w owns 16 channels x full K=1024.
// Protocol: block stores tag t only after block-wide poll of t-1 (barrier) =>
// ping-pong overwrite of tag t-2 is race-free; tags at one address can never
// skip ahead (producer of t+1 must first poll our tag-t granule).
__global__ __launch_bounds__(512) void scan_kernel(
    const float* __restrict__ h0, const float* __restrict__ R,
    const float* __restrict__ decay, float* __restrict__ out,
    u32* __restrict__ hb)
{
    __shared__ __align__(16) _Float16 hst[2][HH];   // ping-pong strip, 4 KB

    const int tid = threadIdx.x;
    const int w = tid >> 6;
    const int l = tid & 63;
    const int ar = l & 15, kg = l >> 4;
    const int b = blockIdx.x & 7, g = blockIdx.x >> 3;

    // ---- one-time A fragments: R row (one channel) x full K, 128 VGPRs ----
    const int chrow = g * CHB + w * 16 + ar;
    f16x8 afrag[32];
#pragma unroll
    for (int s = 0; s < 32; ++s) {
        const float* rp = &R[(size_t)chrow * HH + s * 32 + kg * 8];
        const f32x4 r0 = *(const f32x4*)rp;
        const f32x4 r1 = *(const f32x4*)(rp + 4);
        f16x8 a;
#pragma unroll
        for (int e = 0; e < 4; ++e) { a[e] = (_Float16)r0[e]; a[e + 4] = (_Float16)r1[e]; }
        afrag[s] = a;
    }

    const bool pollme = ((tid >> 6) != g);

    // epilogue lanes: ar<4 handle channel w*16 + kg*4 + ar via acc component ar
    const bool ep = (ar < 4);
    const int ch = g * CHB + w * 16 + kg * 4 + ar;     // valid when ep
    const int chloc = w * 16 + kg * 4 + ar;
    float hp = 0.f, xw_c = 0.f, d_c = 0.f;
    if (ep) {
        hp = h0[(size_t)b * HH + ch];
        xw_c = out[(size_t)b * HH + ch];     // row 0 projection (still intact)
        d_c = decay[(size_t)b * HH + ch];
    }

    for (int t = 0; t < TT; ++t) {
        const int p = t & 1;
        // ---- fill strip p: staggered double-poll of remote granules ----
        if (t == 0) {
            const float2 v = *(const float2*)&h0[(size_t)b * HH + tid * 2];
            *(u32*)&hst[0][tid * 2] = (u32)f16bits(v.x) | ((u32)f16bits(v.y) << 16);
        } else if (pollme) {
            const u32 expt = (u32)(t - 1) << 16;
            const u64 gp = (u64)hb
                         + (u64)(((t - 1) & 1) * (BB * HH) + b * HH + tid * 2) * 4;
            u32x2 gA, gB, gr;
            asm volatile("global_load_dwordx2 %0, %1, off sc0 sc1"
                         : "=v"(gA) : "v"(gp));
            __builtin_amdgcn_s_sleep(4);   // ~256 cyc stagger between the two slots
            asm volatile("global_load_dwordx2 %0, %1, off sc0 sc1"
                         : "=v"(gB) : "v"(gp));
            while (true) {
                asm volatile("s_waitcnt vmcnt(1)" ::: "memory");   // slot A landed
                __builtin_amdgcn_sched_barrier(0);
                if (!(((gA[0] ^ expt) | (gA[1] ^ expt)) & 0xffff0000u)) { gr = gA; break; }
                asm volatile("global_load_dwordx2 %0, %1, off sc0 sc1"
                             : "=v"(gA) : "v"(gp));
                asm volatile("s_waitcnt vmcnt(1)" ::: "memory");   // slot B landed
                __builtin_amdgcn_sched_barrier(0);
                if (!(((gB[0] ^ expt) | (gB[1] ^ expt)) & 0xffff0000u)) { gr = gB; break; }
                asm volatile("global_load_dwordx2 %0, %1, off sc0 sc1"
                             : "=v"(gB) : "v"(gp));
            }
            // drain the still-outstanding slot before its register can be reused
            asm volatile("s_waitcnt vmcnt(0)" ::: "memory");
            __builtin_amdgcn_sched_barrier(0);
            *(u32*)&hst[p][tid * 2] = (gr[0] & 0xffffu) | (gr[1] << 16);
        }
        __syncthreads();   // strip p complete (poll writes + prev epilogue's own-range)

        // ---- prefetch NEXT step's xw/decay (hides under this step) ----
        float xw_n = xw_c, d_n = d_c;
        if (ep && t + 1 < TT) {
            const size_t nidx = (size_t)(t + 1) * (BB * HH) + (size_t)b * HH + ch;
            xw_n = out[nidx];
            d_n = decay[nidx];
        }

        // ---- 32 MFMAs (full K), 4 interleaved chains ----
        f32x4 ac0 = {0.f, 0.f, 0.f, 0.f}, ac1 = ac0, ac2 = ac0, ac3 = ac0;
#pragma unroll
        for (int s = 0; s < 32; s += 4) {
            ac0 = __builtin_amdgcn_mfma_f32_16x16x32_f16(
                      afrag[s + 0], *(const f16x8*)&hst[p][(s + 0) * 32 + kg * 8], ac0, 0, 0, 0);
            ac1 = __builtin_amdgcn_mfma_f32_16x16x32_f16(
                      afrag[s + 1], *(const f16x8*)&hst[p][(s + 1) * 32 + kg * 8], ac1, 0, 0, 0);
            ac2 = __builtin_amdgcn_mfma_f32_16x16x32_f16(
                      afrag[s + 2], *(const f16x8*)&hst[p][(s + 2) * 32 + kg * 8], ac2, 0, 0, 0);
            ac3 = __builtin_amdgcn_mfma_f32_16x16x32_f16(
                      afrag[s + 3], *(const f16x8*)&hst[p][(s + 3) * 32 + kg * 8], ac3, 0, 0, 0);
        }
        const f32x4 acc = (ac0 + ac1) + (ac2 + ac3);

        // ---- epilogue: broadcast FIRST (critical path), then private out store ----
        if (ep) {
            const float s = (ar == 0) ? acc[0] : (ar == 1) ? acc[1]
                          : (ar == 2) ? acc[2] : acc[3];
            const float cand = fast_tanh(s + xw_c);
            const float hnew = d_c * hp + (1.0f - d_c) * cand;
            hp = hnew;
            const u16 hbits = f16bits(hnew);
            const u32 gran = ((u32)t << 16) | (u32)hbits;
            const u64 dst = (u64)hb + (u64)((t & 1) * (BB * HH) + b * HH + ch) * 4;
            asm volatile("global_store_dword %0, %1, off sc0 sc1"
                         :: "v"(dst), "v"(gran) : "memory");
            hst[p ^ 1][g * CHB + chloc] = *(const _Float16*)&hbits;  // own-range shortcut
            out[(size_t)t * (BB * HH) + (size_t)b * HH + ch] = hnew;
        }
        xw_c = xw_n;
        d_c = d_n;
    }
}

// ---------------- launch ----------------
extern "C" void kernel_launch(void* const* d_in, const int* in_sizes, int n_in,
                              void* d_out, int out_size, void* d_ws, size_t ws_size,
                              hipStream_t stream) {
    const float* x    = (const float*)d_in[0];
    const float* h0   = (const float*)d_in[1];
    const float* Wx   = (const float*)d_in[2];
    const float* R    = (const float*)d_in[3];
    const float* bias = (const float*)d_in[4];
    const float* Wd   = (const float*)d_in[5];
    const float* bdel = (const float*)d_in[6];
    float* out = (float*)d_out;

    float* decay = (float*)d_ws;                                 // 64 MiB
    u32* hb = (u32*)((char*)d_ws + (size_t)TT * BB * HH * 4);    // 2 x 32 KiB ping-pong

    clear_hb_kernel<<<64, 256, 0, stream>>>(hb);
    proj_kernel<<<dim3(HH / 64, (TT * BB) / 64), 256, 0, stream>>>(
        x, Wx, Wd, bias, bdel, out, decay);
    scan_kernel<<<64, 512, 0, stream>>>(h0, R, decay, out, hb);
}